// Round 19
// baseline (132.807 us; speedup 1.0000x reference)
//
#include <hip/hip_runtime.h>

typedef unsigned short u16;
typedef unsigned int   u32;
typedef __attribute__((ext_vector_type(8)))  short short8;
typedef __attribute__((ext_vector_type(4)))  float f32x4;
typedef __attribute__((ext_vector_type(16))) float f32x16;
typedef __attribute__((ext_vector_type(2)))  u32 uint2v;
typedef __attribute__((ext_vector_type(4)))  u32 uint4v;

#define DEV __device__ __forceinline__

DEV u16 f2bf(float f) {
    u32 u = __builtin_bit_cast(u32, f);
    return (u16)((u + 0x7fffu + ((u >> 16) & 1u)) >> 16);
}
DEV float bf2f(u32 u) { return __builtin_bit_cast(float, u << 16); }
DEV u32 cvtpk(float a, float b) {
    u32 r;
    asm("v_cvt_pk_bf16_f32 %0, %1, %2" : "=v"(r) : "v"(a), "v"(b));
    return r;
}
typedef const __attribute__((address_space(1))) u32 g_u32;
typedef __attribute__((address_space(3))) u32 l_u32;
DEV void gload16(const u16* g, u16* l) {
    __builtin_amdgcn_global_load_lds((g_u32*)g, (l_u32*)l, 16, 0, 0);
}

// ---------------------------------------------------------------------------
// FRAGMENT-PACKED matrix layout (u16 matrices of width 1024):
//   pidx(r,c) = (((r>>4)*32 + (c>>5))*64 + ((r&15) + 16*((c>>3)&3)))*8 + (c&7)
// 16x32 subtile = 512 u16 (1KB), lane-major: fragment read = base + lane*16B.
// Packed K/V tiles for attention: 4KB per 32-token tile (see prior rounds).
// ---------------------------------------------------------------------------

// GEMM: C[4096,1024] = A @ W + bias, A/B both fragment-packed bf16.
// 128x128 tile, BK=32, 256 thr (4 waves 2x2), 16x16x32 MFMA, m97 staging.
// omode: 0 bf16 row-major (*oscale); 1 packed-V; 2 f32 row-major; 3 packed-K.
DEV void gemm_body(const u16* __restrict__ Apk, const u16* __restrict__ Bpk,
                   const float* __restrict__ bias, float oscale, void* C_,
                   int omode) {
    const int m0 = blockIdx.y * 128, n0 = blockIdx.x * 128;
    const int t = threadIdx.x, lane = t & 63, w = t >> 6;
    const int wm = w >> 1, wn = w & 1;
    const int l15 = lane & 15, l4 = lane >> 4;
    __shared__ __align__(16) u16 As[128 * 32];
    __shared__ __align__(16) u16 Bs[128 * 32];
    f32x4 acc[4][4] = {};

    const int rtA = m0 >> 4, rtB = n0 >> 4;
    for (int k0 = 0; k0 < 1024; k0 += 32) {
        const int ct = k0 >> 5;
        #pragma unroll
        for (int rnd = 0; rnd < 2; rnd++) {
            int cc = rnd * 256 + t, s = cc >> 6, l = cc & 63;
            gload16(Bpk + (size_t)(((rtB + s) * 32 + ct) * 64 + l) * 8, Bs + cc * 8);
            gload16(Apk + (size_t)(((rtA + s) * 32 + ct) * 64 + l) * 8, As + cc * 8);
        }
        __syncthreads();
        short8 af[4], bfr[4];
        #pragma unroll
        for (int i = 0; i < 4; i++) {
            af[i]  = *(const short8*)(As + ((wm * 4 + i) * 64 + lane) * 8);
            bfr[i] = *(const short8*)(Bs + ((wn * 4 + i) * 64 + lane) * 8);
        }
        #pragma unroll
        for (int i = 0; i < 4; i++)
            #pragma unroll
            for (int j = 0; j < 4; j++)
                acc[i][j] = __builtin_amdgcn_mfma_f32_16x16x32_bf16(af[i], bfr[j], acc[i][j], 0, 0, 0);
        __syncthreads();
    }

    #pragma unroll
    for (int i = 0; i < 4; i++) {
        #pragma unroll
        for (int j = 0; j < 4; j++) {
            int col = n0 + wn * 64 + j * 16 + l15;
            int mb  = m0 + wm * 64 + i * 16 + l4 * 4;
            float bv = bias[col];
            if (omode == 2) {
                float* C = (float*)C_;
                #pragma unroll
                for (int r = 0; r < 4; r++)
                    C[(size_t)(mb + r) * 1024 + col] = acc[i][j][r] + bv;
            } else if (omode == 0) {
                u16* C = (u16*)C_;
                #pragma unroll
                for (int r = 0; r < 4; r++)
                    C[(size_t)(mb + r) * 1024 + col] = f2bf((acc[i][j][r] + bv) * oscale);
            } else if (omode == 3) {
                // packed K tiles
                u16* C = (u16*)C_;
                int hh = col >> 6, dd = col & 63;
                int bb = mb >> 11, tt = mb & 2047;
                size_t tile = ((size_t)(bb * 16 + hh) * 64 + (tt >> 5)) * 2048;
                int c = dd >> 4, hi2 = (dd >> 3) & 1, e = dd & 7;
                int lob = tt & 31;
                #pragma unroll
                for (int r = 0; r < 4; r++)
                    C[tile + (size_t)((c * 2 + hi2) * 32 + lob + r) * 8 + e] =
                        f2bf(acc[i][j][r] + bv);
            } else {
                // packed V tiles: 4 consecutive tokens are contiguous elems
                u16* C = (u16*)C_;
                int hh = col >> 6, dd = col & 63;
                int bb = mb >> 11, tt = mb & 2047;
                size_t tile = ((size_t)(bb * 16 + hh) * 64 + (tt >> 5)) * 2048;
                int tin = tt & 31, kc = tin >> 4, hi2 = (tin >> 3) & 1, e0 = tin & 7;
                int c2 = dd >> 5, lo2 = dd & 31;
                size_t off = tile + (size_t)((kc * 2 + c2) * 64 + hi2 * 32 + lo2) * 8 + e0;
                uint2v pp;
                pp[0] = cvtpk(acc[i][j][0] + bv, acc[i][j][1] + bv);
                pp[1] = cvtpk(acc[i][j][2] + bv, acc[i][j][3] + bv);
                *(uint2v*)(C + off) = pp;
            }
        }
    }
}

// weights: W[k][n] f32 -> Wt fragment-packed bf16 (row=n, col=k)
__global__ __launch_bounds__(256) void k_transw(const float* Wq, const float* Wk,
                                                const float* Wv, const float* Wo, u16* Wt) {
    int z = blockIdx.z;
    const float* W = z == 0 ? Wq : z == 1 ? Wk : z == 2 ? Wv : Wo;
    u16* O = Wt + (size_t)z * 1048576;
    __shared__ float tile[32][33];
    int n0 = blockIdx.x * 32, k0 = blockIdx.y * 32;
    int tx = threadIdx.x, ty = threadIdx.y;
    #pragma unroll
    for (int i = 0; i < 32; i += 8) tile[ty + i][tx] = W[(size_t)(k0 + ty + i) * 1024 + n0 + tx];
    __syncthreads();
    #pragma unroll
    for (int i = 0; i < 32; i += 8) {
        int n = n0 + ty + i, k = k0 + tx;
        size_t pi = ((size_t)((n >> 4) * 32 + (k >> 5)) * 64
                     + ((n & 15) + 16 * ((k >> 3) & 3))) * 8 + (k & 7);
        O[pi] = f2bf(tile[tx][ty + i]);
    }
}

// q,k,v f32 -> fragment-packed bf16, OUTPUT-COALESCED: thread id -> subtile
// sub = id>>6, lane = id&63; wave writes one contiguous 1KB subtile.
__global__ __launch_bounds__(256) void k_cvt(const float* q, const float* k, const float* v,
                                             u16* Abf) {
    int z = blockIdx.z;
    const float* src = z == 0 ? q : z == 1 ? k : v;
    u16* dst = Abf + (size_t)z * 4194304;
    int id = (int)blockIdx.x * 256 + threadIdx.x;
    int sub = id >> 6, lane = id & 63;
    int row = (sub >> 5) * 16 + (lane & 15);
    int col = (sub & 31) * 32 + (lane >> 4) * 8;
    const float* sp = src + (size_t)row * 1024 + col;
    float4 a = *(const float4*)sp;
    float4 b = *(const float4*)(sp + 4);
    uint4v o;
    o[0] = cvtpk(a.x, a.y); o[1] = cvtpk(a.z, a.w);
    o[2] = cvtpk(b.x, b.y); o[3] = cvtpk(b.z, b.w);
    *(uint4v*)(dst + (size_t)sub * 512 + lane * 8) = o;
}

__global__ __launch_bounds__(256) void k_proj(const u16* Abf, const u16* Wt,
                                              const float* bq, const float* bk,
                                              const float* bv, u16* QKV) {
    int z = blockIdx.z;
    const u16* A_ = Abf + (size_t)z * 4194304;
    const u16* B_ = Wt + (size_t)z * 1048576;
    const float* bias = z == 0 ? bq : z == 1 ? bk : bv;
    int omode = z == 0 ? 0 : (z == 1 ? 3 : 1);
    // softmax scale AND log2(e) folded into Q so attn uses exp2 directly
    float oscale = z == 0 ? 0.125f * 1.44269504088896f : 1.f;
    void* C_ = QKV + (size_t)z * 4194304;
    gemm_body(A_, B_, bias, oscale, C_, omode);   // single call site: one 16KB LDS
}

// combine 3 pre-normalized bf16 partials -> fragment-packed Xc,
// OUTPUT-COALESCED (wave writes one contiguous 1KB subtile).
__global__ __launch_bounds__(256) void k_combine(const u16* Xp, const float* Lp, u16* Xc) {
    int id = (int)blockIdx.x * 256 + threadIdx.x;
    int sub = id >> 6, lane = id & 63;
    int row = (sub >> 5) * 16 + (lane & 15);
    int col = (sub & 31) * 32 + (lane >> 4) * 8;
    int hh = col >> 6;
    size_t gi = (size_t)row * 1024 + col;
    float l0 = Lp[(size_t)row * 16 + hh];
    float l1 = Lp[65536 + (size_t)row * 16 + hh];
    float l2 = Lp[131072 + (size_t)row * 16 + hh];
    float s = 1.0f / (l0 + l1 + l2);
    float w0 = l0 * s, w1 = l1 * s, w2 = l2 * s;
    uint4v x0 = *(const uint4v*)(Xp + gi);
    uint4v x1 = *(const uint4v*)(Xp + (size_t)4194304 + gi);
    uint4v x2 = *(const uint4v*)(Xp + (size_t)2 * 4194304 + gi);
    uint4v o;
    #pragma unroll
    for (int j = 0; j < 4; j++) {
        float a0 = bf2f(x0[j] & 0xffffu) * w0 + bf2f(x1[j] & 0xffffu) * w1
                 + bf2f(x2[j] & 0xffffu) * w2;
        float a1 = bf2f(x0[j] >> 16) * w0 + bf2f(x1[j] >> 16) * w1
                 + bf2f(x2[j] >> 16) * w2;
        o[j] = cvtpk(a0, a1);
    }
    *(uint4v*)(Xc + (size_t)sub * 512 + lane * 8) = o;
}

__global__ __launch_bounds__(256) void k_gemm_out(const u16* Xc, const u16* Wt,
                                                  const float* bo, float* out) {
    gemm_body(Xc, Wt, bo, 1.f, out, 2);
}

// ---------------------------------------------------------------------------
// Causal flash attention v12: ZIGZAG Q-PAIRING on the R18 skeleton.
// k_attn is L2-BW-bound (66.5K wave-tiles x 16KB = 1.09 GB of L2 reads =
// 31.6us floor at 34.5 TB/s). Fix: each wave owns TWO q-tiles, zigzag pair
// (m', 63-m') with m' = 4j' + w -- one K/V load serves chain B (always) and
// chain A on the overlap (kt < m'+1). Loads drop to 0.75x; compute per wave
// is EXACTLY 65/3 tiles -> perfectly uniform. Grid 768 blocks = 3 blocks/CU,
// fully resident, zero stragglers. Sequential chains share one S register
// block (VGPR ~158, 3 waves/SIMD). Barrier-free; XCD-local bh = id & 31;
// parity split x3; pre-normalized bf16 partials (combine unchanged).
// ---------------------------------------------------------------------------
__global__ __launch_bounds__(256, 3) void k_attn(const u16* __restrict__ Qp,
                                                 const u16* __restrict__ Kp2,
                                                 const u16* __restrict__ Vp2,
                                                 u16* __restrict__ Xp, float* __restrict__ Lp) {
    const int id = (int)blockIdx.x;
    const int bh = id & 31;                    // same-XCD family (id mod 8 fixed)
    const int rest = id >> 5;                  // 0..23
    const int par = rest % 3;                  // 0..2
    const int jp = rest / 3;                   // 0..7 (uniform blocks: no ordering needed)
    const int b = bh >> 4, h = bh & 15;
    const int t = threadIdx.x, lane = t & 63, w = t >> 6;
    const int lo = lane & 31, hi = lane >> 5;
    const int mp = 4 * jp + w;                 // pair index 0..31
    const int qta = mp, qtb = 63 - mp;         // zigzag pair (qta < qtb)
    const int q0a = qta * 32, q0b = qtb * 32;
    const int NTa = qta + 1, NTb = qtb + 1;    // causal k-tiles per chain
    const u16* Qb = Qp + (size_t)(b * 2048) * 1024 + h * 64;
    const u16* Kb = Kp2 + (size_t)bh * 64 * 2048;
    const u16* Vb = Vp2 + (size_t)bh * 64 * 2048;

    short8 qfa[4], qfb[4];
    #pragma unroll
    for (int c = 0; c < 4; c++) {
        qfa[c] = *(const short8*)(Qb + (size_t)(q0a + lo) * 1024 + c * 16 + hi * 8);
        qfb[c] = *(const short8*)(Qb + (size_t)(q0b + lo) * 1024 + c * 16 + hi * 8);
    }

    f32x16 O0a = {}, O1a = {}, O0b = {}, O1b = {};
    float lsa = 0.f, lsb = 0.f;
    const int qga = q0a + lo, qgb = q0b + lo;

#define LOADKV(KF, VF, kt) do {                                                          \
        const u16* kt_ = Kb + (size_t)(kt) * 2048;                                       \
        const u16* vt_ = Vb + (size_t)(kt) * 2048;                                       \
        _Pragma("unroll")                                                                \
        for (int c = 0; c < 4; c++)                                                      \
            KF[c] = *(const short8*)(kt_ + c * 512 + lane * 8);                          \
        _Pragma("unroll")                                                                \
        for (int jj = 0; jj < 4; jj++)                                                   \
            VF[jj] = *(const short8*)(vt_ + jj * 512 + lane * 8);                        \
    } while (0)

#define QKM(S, KF, QF) do {                                                              \
        S = (f32x16){};                                                                  \
        _Pragma("unroll")                                                                \
        for (int c = 0; c < 4; c++)                                                      \
            S = __builtin_amdgcn_mfma_f32_32x32x16_bf16(KF[c], QF[c], S, 0, 0, 0);       \
    } while (0)

#define SMPV(S, O0, O1, lsum, NT, qg, kt, VF) do {                                        \
        const bool diag = ((kt) == (NT) - 1);                                             \
        _Pragma("unroll")                                                                 \
        for (int kc = 0; kc < 2; kc++) {                                                  \
            float pv[8];                                                                  \
            _Pragma("unroll")                                                             \
            for (int jj = 0; jj < 8; jj++) {                                              \
                int r = kc * 8 + jj;                                                      \
                float s = S[r];                                                           \
                if (diag) {                                                               \
                    int kg = (kt) * 32 + (r & 3) + 8 * (r >> 2) + 4 * hi;                 \
                    s = (kg <= (qg)) ? s : -1e30f;                                        \
                }                                                                         \
                pv[jj] = __builtin_amdgcn_exp2f(s);                                       \
            }                                                                             \
            lsum += (((pv[0] + pv[1]) + (pv[2] + pv[3])) +                                \
                     ((pv[4] + pv[5]) + (pv[6] + pv[7])));                                \
            u32 w0 = cvtpk(pv[0], pv[1]), w1 = cvtpk(pv[2], pv[3]);                       \
            u32 w2 = cvtpk(pv[4], pv[5]), w3 = cvtpk(pv[6], pv[7]);                       \
            auto r0 = __builtin_amdgcn_permlane32_swap(w0, w2, false, false);             \
            auto r1 = __builtin_amdgcn_permlane32_swap(w1, w3, false, false);             \
            uint4v fw; fw[0] = r0[0]; fw[1] = r1[0]; fw[2] = r0[1]; fw[3] = r1[1];        \
            short8 pf = __builtin_bit_cast(short8, fw);                                   \
            O0 = __builtin_amdgcn_mfma_f32_32x32x16_bf16(pf, VF[kc * 2 + 0], O0, 0, 0, 0);\
            O1 = __builtin_amdgcn_mfma_f32_32x32x16_bf16(pf, VF[kc * 2 + 1], O1, 0, 0, 0);\
        }                                                                                 \
    } while (0)

    {
        short8 kf[4], vf[4];
        f32x16 S;
        for (int kt = par; kt < NTb; kt += 3) {
            LOADKV(kf, vf, kt);
            QKM(S, kf, qfb);
            SMPV(S, O0b, O1b, lsb, NTb, qgb, kt, vf);
            if (kt < NTa) {
                QKM(S, kf, qfa);
                SMPV(S, O0a, O1a, lsa, NTa, qga, kt, vf);
            }
        }
    }
#undef LOADKV
#undef QKM
#undef SMPV

    // pre-normalized partial outputs; empty parity ranges write zeros (lt=0)
    u16* Xb = Xp + (size_t)par * 4194304;
#define EPI(O0, O1, lsum, q0) do {                                                        \
        float ltot = (lsum) + __shfl_xor((lsum), 32, 64);                                 \
        _Pragma("unroll")                                                                 \
        for (int r = 0; r < 16; r++) {                                                    \
            int qr = (r & 3) + 8 * (r >> 2) + 4 * hi;                                     \
            float lt = __shfl(ltot, qr, 64);                                              \
            float linv = lt > 0.f ? 1.f / lt : 0.f;                                       \
            size_t rowb = (size_t)(b * 2048 + (q0) + qr) * 1024 + h * 64;                 \
            Xb[rowb + lo]      = f2bf(O0[r] * linv);                                      \
            Xb[rowb + 32 + lo] = f2bf(O1[r] * linv);                                      \
        }                                                                                 \
        if (hi == 0)                                                                      \
            Lp[(size_t)par * 65536 + (size_t)(b * 2048 + (q0) + lo) * 16 + h] = ltot;     \
    } while (0)

    EPI(O0a, O1a, lsa, q0a);
    EPI(O0b, O1b, lsb, q0b);
#undef EPI
}

extern "C" void kernel_launch(void* const* d_in, const int* in_sizes, int n_in,
                              void* d_out, int out_size, void* d_ws, size_t ws_size,
                              hipStream_t stream) {
    (void)in_sizes; (void)n_in; (void)out_size; (void)ws_size;
    const float* q  = (const float*)d_in[0];
    const float* k  = (const float*)d_in[1];
    const float* v  = (const float*)d_in[2];
    const float* Wq = (const float*)d_in[3];
    const float* bq = (const float*)d_in[4];
    const float* Wk = (const float*)d_in[5];
    const float* bk = (const float*)d_in[6];
    const float* Wv = (const float*)d_in[7];
    const float* bv = (const float*)d_in[8];
    const float* Wo = (const float*)d_in[9];
    const float* bo = (const float*)d_in[10];

    // workspace layout (u16 units):
    //   [0, 4M)       Wt  : 4 x 1024x1024 bf16, fragment-packed  (8 MB)
    //   [4M, 16M)     QKV : Q row-major, K packed, V packed      (24 MB)
    //                 Q seg reused as Xc (fragment-packed) after k_attn
    //   [16M, 28M)    Abf : q,k,v fragment-packed bf16 (dead after k_proj)
    //                 reused: Xp = Abf (3 segs of 4M)
    //   [28M, +768KB) Lp  : 3 x 4096x16 f32
    u16*   Wt  = (u16*)d_ws;
    u16*   QKV = Wt + (size_t)4 * 1048576;
    u16*   Abf = QKV + (size_t)3 * 4194304;
    u16*   Xp  = Abf;                         // reuse (Abf dead after k_proj)
    u16*   Xc  = QKV;                         // reuse Q segment (dead after k_attn)
    float* Lp  = (float*)(Abf + (size_t)3 * 4194304);

    k_transw<<<dim3(32, 32, 4), dim3(32, 8), 0, stream>>>(Wq, Wk, Wv, Wo, Wt);
    k_cvt<<<dim3(2048, 1, 3), 256, 0, stream>>>(q, k, v, Abf);
    k_proj<<<dim3(8, 32, 3), 256, 0, stream>>>(Abf, Wt, bq, bk, bv, QKV);
    k_attn<<<dim3(768), 256, 0, stream>>>(QKV, QKV + (size_t)4194304,
                                          QKV + (size_t)2 * 4194304, Xp, Lp);
    k_combine<<<2048, 256, 0, stream>>>(Xp, Lp, Xc);
    k_gemm_out<<<dim3(8, 32), 256, 0, stream>>>(Xc, Wt + (size_t)3 * 1048576,
                                                bo, (float*)d_out);
}

// Round 20
// 120.046 us; speedup vs baseline: 1.1063x; 1.1063x over previous
//
#include <hip/hip_runtime.h>

typedef unsigned short u16;
typedef unsigned int   u32;
typedef __attribute__((ext_vector_type(8)))  short short8;
typedef __attribute__((ext_vector_type(4)))  float f32x4;
typedef __attribute__((ext_vector_type(16))) float f32x16;
typedef __attribute__((ext_vector_type(2)))  u32 uint2v;
typedef __attribute__((ext_vector_type(4)))  u32 uint4v;

#define DEV __device__ __forceinline__

DEV u16 f2bf(float f) {
    u32 u = __builtin_bit_cast(u32, f);
    return (u16)((u + 0x7fffu + ((u >> 16) & 1u)) >> 16);
}
DEV float bf2f(u32 u) { return __builtin_bit_cast(float, u << 16); }
DEV u32 cvtpk(float a, float b) {
    u32 r;
    asm("v_cvt_pk_bf16_f32 %0, %1, %2" : "=v"(r) : "v"(a), "v"(b));
    return r;
}
typedef const __attribute__((address_space(1))) u32 g_u32;
typedef __attribute__((address_space(3))) u32 l_u32;
DEV void gload16(const u16* g, u16* l) {
    __builtin_amdgcn_global_load_lds((g_u32*)g, (l_u32*)l, 16, 0, 0);
}

// ---------------------------------------------------------------------------
// FRAGMENT-PACKED matrix layout (u16 matrices of width 1024):
//   pidx(r,c) = (((r>>4)*32 + (c>>5))*64 + ((r&15) + 16*((c>>3)&3)))*8 + (c&7)
// 16x32 subtile = 512 u16 (1KB), lane-major: fragment read = base + lane*16B.
// Packed K/V tiles for attention: 4KB per 32-token tile (see prior rounds).
// ---------------------------------------------------------------------------

// GEMM: C[4096,1024] = A @ W + bias, A/B both fragment-packed bf16.
// 128x128 tile, BK=32, 256 thr (4 waves 2x2), 16x16x32 MFMA, m97 staging.
// omode: 0 bf16 row-major (*oscale); 1 packed-V; 2 f32 row-major; 3 packed-K.
DEV void gemm_body(const u16* __restrict__ Apk, const u16* __restrict__ Bpk,
                   const float* __restrict__ bias, float oscale, void* C_,
                   int omode) {
    const int m0 = blockIdx.y * 128, n0 = blockIdx.x * 128;
    const int t = threadIdx.x, lane = t & 63, w = t >> 6;
    const int wm = w >> 1, wn = w & 1;
    const int l15 = lane & 15, l4 = lane >> 4;
    __shared__ __align__(16) u16 As[128 * 32];
    __shared__ __align__(16) u16 Bs[128 * 32];
    f32x4 acc[4][4] = {};

    const int rtA = m0 >> 4, rtB = n0 >> 4;
    for (int k0 = 0; k0 < 1024; k0 += 32) {
        const int ct = k0 >> 5;
        #pragma unroll
        for (int rnd = 0; rnd < 2; rnd++) {
            int cc = rnd * 256 + t, s = cc >> 6, l = cc & 63;
            gload16(Bpk + (size_t)(((rtB + s) * 32 + ct) * 64 + l) * 8, Bs + cc * 8);
            gload16(Apk + (size_t)(((rtA + s) * 32 + ct) * 64 + l) * 8, As + cc * 8);
        }
        __syncthreads();
        short8 af[4], bfr[4];
        #pragma unroll
        for (int i = 0; i < 4; i++) {
            af[i]  = *(const short8*)(As + ((wm * 4 + i) * 64 + lane) * 8);
            bfr[i] = *(const short8*)(Bs + ((wn * 4 + i) * 64 + lane) * 8);
        }
        #pragma unroll
        for (int i = 0; i < 4; i++)
            #pragma unroll
            for (int j = 0; j < 4; j++)
                acc[i][j] = __builtin_amdgcn_mfma_f32_16x16x32_bf16(af[i], bfr[j], acc[i][j], 0, 0, 0);
        __syncthreads();
    }

    #pragma unroll
    for (int i = 0; i < 4; i++) {
        #pragma unroll
        for (int j = 0; j < 4; j++) {
            int col = n0 + wn * 64 + j * 16 + l15;
            int mb  = m0 + wm * 64 + i * 16 + l4 * 4;
            float bv = bias[col];
            if (omode == 2) {
                float* C = (float*)C_;
                #pragma unroll
                for (int r = 0; r < 4; r++)
                    C[(size_t)(mb + r) * 1024 + col] = acc[i][j][r] + bv;
            } else if (omode == 0) {
                u16* C = (u16*)C_;
                #pragma unroll
                for (int r = 0; r < 4; r++)
                    C[(size_t)(mb + r) * 1024 + col] = f2bf((acc[i][j][r] + bv) * oscale);
            } else if (omode == 3) {
                // packed K tiles
                u16* C = (u16*)C_;
                int hh = col >> 6, dd = col & 63;
                int bb = mb >> 11, tt = mb & 2047;
                size_t tile = ((size_t)(bb * 16 + hh) * 64 + (tt >> 5)) * 2048;
                int c = dd >> 4, hi2 = (dd >> 3) & 1, e = dd & 7;
                int lob = tt & 31;
                #pragma unroll
                for (int r = 0; r < 4; r++)
                    C[tile + (size_t)((c * 2 + hi2) * 32 + lob + r) * 8 + e] =
                        f2bf(acc[i][j][r] + bv);
            } else {
                // packed V tiles: 4 consecutive tokens are contiguous elems
                u16* C = (u16*)C_;
                int hh = col >> 6, dd = col & 63;
                int bb = mb >> 11, tt = mb & 2047;
                size_t tile = ((size_t)(bb * 16 + hh) * 64 + (tt >> 5)) * 2048;
                int tin = tt & 31, kc = tin >> 4, hi2 = (tin >> 3) & 1, e0 = tin & 7;
                int c2 = dd >> 5, lo2 = dd & 31;
                size_t off = tile + (size_t)((kc * 2 + c2) * 64 + hi2 * 32 + lo2) * 8 + e0;
                uint2v pp;
                pp[0] = cvtpk(acc[i][j][0] + bv, acc[i][j][1] + bv);
                pp[1] = cvtpk(acc[i][j][2] + bv, acc[i][j][3] + bv);
                *(uint2v*)(C + off) = pp;
            }
        }
    }
}

// FUSED prep: id < 6144 -> q/k/v f32 -> fragment-packed bf16 (output-coalesced,
// wave writes one contiguous 1KB subtile); id >= 6144 -> weight transpose+pack
// W[k][n] f32 -> Wt fragment-packed bf16 (row=n, col=k). Outputs disjoint.
__global__ __launch_bounds__(256) void k_prep(const float* q, const float* k, const float* v,
                                              const float* Wq, const float* Wk,
                                              const float* Wv, const float* Wo,
                                              u16* Abf, u16* Wt) {
    int id = (int)blockIdx.x;
    int t = threadIdx.x;
    if (id < 6144) {
        // cvt path (was k_cvt): z = id/2048, block = id%2048
        int z = id >> 11, xb = id & 2047;
        const float* src = z == 0 ? q : z == 1 ? k : v;
        u16* dst = Abf + (size_t)z * 4194304;
        int gid = xb * 256 + t;
        int sub = gid >> 6, lane = gid & 63;
        int row = (sub >> 5) * 16 + (lane & 15);
        int col = (sub & 31) * 32 + (lane >> 4) * 8;
        const float* sp = src + (size_t)row * 1024 + col;
        float4 a = *(const float4*)sp;
        float4 b = *(const float4*)(sp + 4);
        uint4v o;
        o[0] = cvtpk(a.x, a.y); o[1] = cvtpk(a.z, a.w);
        o[2] = cvtpk(b.x, b.y); o[3] = cvtpk(b.z, b.w);
        *(uint4v*)(dst + (size_t)sub * 512 + lane * 8) = o;
    } else {
        // transw path (was k_transw): 4096 blocks, z = idb/1024
        int idb = id - 6144;
        int z = idb >> 10, rem = idb & 1023;
        const float* W = z == 0 ? Wq : z == 1 ? Wk : z == 2 ? Wv : Wo;
        u16* O = Wt + (size_t)z * 1048576;
        __shared__ float tile[32][33];
        int n0 = (rem & 31) * 32, k0 = (rem >> 5) * 32;
        int tx = t & 31, ty = t >> 5;
        #pragma unroll
        for (int i = 0; i < 32; i += 8)
            tile[ty + i][tx] = W[(size_t)(k0 + ty + i) * 1024 + n0 + tx];
        __syncthreads();
        #pragma unroll
        for (int i = 0; i < 32; i += 8) {
            int n = n0 + ty + i, kk = k0 + tx;
            size_t pi = ((size_t)((n >> 4) * 32 + (kk >> 5)) * 64
                         + ((n & 15) + 16 * ((kk >> 3) & 3))) * 8 + (kk & 7);
            O[pi] = f2bf(tile[tx][ty + i]);
        }
    }
}

__global__ __launch_bounds__(256) void k_proj(const u16* Abf, const u16* Wt,
                                              const float* bq, const float* bk,
                                              const float* bv, u16* QKV) {
    int z = blockIdx.z;
    const u16* A_ = Abf + (size_t)z * 4194304;
    const u16* B_ = Wt + (size_t)z * 1048576;
    const float* bias = z == 0 ? bq : z == 1 ? bk : bv;
    int omode = z == 0 ? 0 : (z == 1 ? 3 : 1);
    // softmax scale AND log2(e) folded into Q so attn uses exp2 directly
    float oscale = z == 0 ? 0.125f * 1.44269504088896f : 1.f;
    void* C_ = QKV + (size_t)z * 4194304;
    gemm_body(A_, B_, bias, oscale, C_, omode);   // single call site: one 16KB LDS
}

// combine 3 pre-normalized bf16 partials -> fragment-packed Xc,
// OUTPUT-COALESCED (wave writes one contiguous 1KB subtile).
__global__ __launch_bounds__(256) void k_combine(const u16* Xp, const float* Lp, u16* Xc) {
    int id = (int)blockIdx.x * 256 + threadIdx.x;
    int sub = id >> 6, lane = id & 63;
    int row = (sub >> 5) * 16 + (lane & 15);
    int col = (sub & 31) * 32 + (lane >> 4) * 8;
    int hh = col >> 6;
    size_t gi = (size_t)row * 1024 + col;
    float l0 = Lp[(size_t)row * 16 + hh];
    float l1 = Lp[65536 + (size_t)row * 16 + hh];
    float l2 = Lp[131072 + (size_t)row * 16 + hh];
    float s = 1.0f / (l0 + l1 + l2);
    float w0 = l0 * s, w1 = l1 * s, w2 = l2 * s;
    uint4v x0 = *(const uint4v*)(Xp + gi);
    uint4v x1 = *(const uint4v*)(Xp + (size_t)4194304 + gi);
    uint4v x2 = *(const uint4v*)(Xp + (size_t)2 * 4194304 + gi);
    uint4v o;
    #pragma unroll
    for (int j = 0; j < 4; j++) {
        float a0 = bf2f(x0[j] & 0xffffu) * w0 + bf2f(x1[j] & 0xffffu) * w1
                 + bf2f(x2[j] & 0xffffu) * w2;
        float a1 = bf2f(x0[j] >> 16) * w0 + bf2f(x1[j] >> 16) * w1
                 + bf2f(x2[j] >> 16) * w2;
        o[j] = cvtpk(a0, a1);
    }
    *(uint4v*)(Xc + (size_t)sub * 512 + lane * 8) = o;
}

__global__ __launch_bounds__(256) void k_gemm_out(const u16* Xc, const u16* Wt,
                                                  const float* bo, float* out) {
    gemm_body(Xc, Wt, bo, 1.f, out, 2);
}

// ---------------------------------------------------------------------------
// Causal flash attention (R18-verified, byte-identical): barrier-free register
// kernel; a block's 4 waves own CONSECUTIVE q-tiles (qt = 4j + w, within-block
// spread <= 1 parity-tile) and heavy blocks dispatch FIRST (j = 15 - rest/3)
// so the CP backfills light blocks into the tail. XCD-local bh = id & 31;
// k-split x3; pre-normalized bf16 partials + f32 lsum; combine merges.
// ---------------------------------------------------------------------------
__global__ __launch_bounds__(256, 3) void k_attn(const u16* __restrict__ Qp,
                                                 const u16* __restrict__ Kp2,
                                                 const u16* __restrict__ Vp2,
                                                 u16* __restrict__ Xp, float* __restrict__ Lp) {
    const int id = (int)blockIdx.x;
    const int bh = id & 31;                    // same-XCD family (id mod 8 fixed)
    const int rest = id >> 5;                  // 0..47
    const int par = rest % 3;                  // 0..2
    const int j = 15 - rest / 3;               // heavy-first: low id -> high j
    const int b = bh >> 4, h = bh & 15;
    const int t = threadIdx.x, lane = t & 63, w = t >> 6;
    const int lo = lane & 31, hi = lane >> 5;
    const int qt = 4 * j + w;                  // consecutive q-tiles per block
    const int q0 = qt * 32;
    const int NTw = qt + 1;                    // this wave's causal k-tiles
    const u16* Qb = Qp + (size_t)(b * 2048) * 1024 + h * 64;
    const u16* Kb = Kp2 + (size_t)bh * 64 * 2048;
    const u16* Vb = Vp2 + (size_t)bh * 64 * 2048;

    short8 qf[4];
    #pragma unroll
    for (int c = 0; c < 4; c++)
        qf[c] = *(const short8*)(Qb + (size_t)(q0 + lo) * 1024 + c * 16 + hi * 8);

    f32x16 O0 = {}, O1 = {};
    float lsum = 0.f;
    const int qg = q0 + lo;

#define LOADKV(KF, VF, kt) do {                                                          \
        const u16* kt_ = Kb + (size_t)(kt) * 2048;                                       \
        const u16* vt_ = Vb + (size_t)(kt) * 2048;                                       \
        _Pragma("unroll")                                                                \
        for (int c = 0; c < 4; c++)                                                      \
            KF[c] = *(const short8*)(kt_ + c * 512 + lane * 8);                          \
        _Pragma("unroll")                                                                \
        for (int jj = 0; jj < 4; jj++)                                                   \
            VF[jj] = *(const short8*)(vt_ + jj * 512 + lane * 8);                        \
    } while (0)

#define COMPUTE(KF, VF, kt) do {                                                          \
        f32x16 S = {};                                                                    \
        _Pragma("unroll")                                                                 \
        for (int c = 0; c < 4; c++)                                                       \
            S = __builtin_amdgcn_mfma_f32_32x32x16_bf16(KF[c], qf[c], S, 0, 0, 0);        \
        const bool diag = ((kt) == NTw - 1);                                              \
        _Pragma("unroll")                                                                 \
        for (int kc = 0; kc < 2; kc++) {                                                  \
            float pv[8];                                                                  \
            _Pragma("unroll")                                                             \
            for (int jj = 0; jj < 8; jj++) {                                              \
                int r = kc * 8 + jj;                                                      \
                float s = S[r];                                                           \
                if (diag) {                                                               \
                    int kg = (kt) * 32 + (r & 3) + 8 * (r >> 2) + 4 * hi;                 \
                    s = (kg <= qg) ? s : -1e30f;                                          \
                }                                                                         \
                pv[jj] = __builtin_amdgcn_exp2f(s);                                       \
            }                                                                             \
            lsum += (((pv[0] + pv[1]) + (pv[2] + pv[3])) +                                \
                     ((pv[4] + pv[5]) + (pv[6] + pv[7])));                                \
            u32 w0 = cvtpk(pv[0], pv[1]), w1 = cvtpk(pv[2], pv[3]);                       \
            u32 w2 = cvtpk(pv[4], pv[5]), w3 = cvtpk(pv[6], pv[7]);                       \
            auto r0 = __builtin_amdgcn_permlane32_swap(w0, w2, false, false);             \
            auto r1 = __builtin_amdgcn_permlane32_swap(w1, w3, false, false);             \
            uint4v fw; fw[0] = r0[0]; fw[1] = r1[0]; fw[2] = r0[1]; fw[3] = r1[1];        \
            short8 pf = __builtin_bit_cast(short8, fw);                                   \
            O0 = __builtin_amdgcn_mfma_f32_32x32x16_bf16(pf, VF[kc * 2 + 0], O0, 0, 0, 0);\
            O1 = __builtin_amdgcn_mfma_f32_32x32x16_bf16(pf, VF[kc * 2 + 1], O1, 0, 0, 0);\
        }                                                                                 \
    } while (0)

    {
        short8 kf0[4], vf0[4], kf1[4], vf1[4];
        int kt = par;
        if (kt < NTw) {
            LOADKV(kf0, vf0, kt);
            while (true) {
                if (kt + 3 < NTw) LOADKV(kf1, vf1, kt + 3);
                COMPUTE(kf0, vf0, kt);
                kt += 3;
                if (kt >= NTw) break;
                if (kt + 3 < NTw) LOADKV(kf0, vf0, kt + 3);
                COMPUTE(kf1, vf1, kt);
                kt += 3;
                if (kt >= NTw) break;
            }
        }
    }
#undef LOADKV
#undef COMPUTE

    // pre-normalized partial output; empty parity ranges write zeros (lt=0)
    float ltot = lsum + __shfl_xor(lsum, 32, 64);
    u16* Xb = Xp + (size_t)par * 4194304;
    #pragma unroll
    for (int r = 0; r < 16; r++) {
        int qr = (r & 3) + 8 * (r >> 2) + 4 * hi;
        float lt = __shfl(ltot, qr, 64);       // normalizer of q-row qr
        float linv = lt > 0.f ? 1.f / lt : 0.f;
        size_t rowb = (size_t)(b * 2048 + q0 + qr) * 1024 + h * 64;
        Xb[rowb + lo]      = f2bf(O0[r] * linv);
        Xb[rowb + 32 + lo] = f2bf(O1[r] * linv);
    }
    if (hi == 0)
        Lp[(size_t)par * 65536 + (size_t)(b * 2048 + q0 + lo) * 16 + h] = ltot;
}

extern "C" void kernel_launch(void* const* d_in, const int* in_sizes, int n_in,
                              void* d_out, int out_size, void* d_ws, size_t ws_size,
                              hipStream_t stream) {
    (void)in_sizes; (void)n_in; (void)out_size; (void)ws_size;
    const float* q  = (const float*)d_in[0];
    const float* k  = (const float*)d_in[1];
    const float* v  = (const float*)d_in[2];
    const float* Wq = (const float*)d_in[3];
    const float* bq = (const float*)d_in[4];
    const float* Wk = (const float*)d_in[5];
    const float* bk = (const float*)d_in[6];
    const float* Wv = (const float*)d_in[7];
    const float* bv = (const float*)d_in[8];
    const float* Wo = (const float*)d_in[9];
    const float* bo = (const float*)d_in[10];

    // workspace layout (u16 units):
    //   [0, 4M)       Wt  : 4 x 1024x1024 bf16, fragment-packed  (8 MB)
    //   [4M, 16M)     QKV : Q row-major, K packed, V packed      (24 MB)
    //                 Q seg reused as Xc (fragment-packed) after k_attn
    //   [16M, 28M)    Abf : q,k,v fragment-packed bf16 (dead after k_proj)
    //                 reused: Xp = Abf (3 segs of 4M)
    //   [28M, +768KB) Lp  : 3 x 4096x16 f32
    u16*   Wt  = (u16*)d_ws;
    u16*   QKV = Wt + (size_t)4 * 1048576;
    u16*   Abf = QKV + (size_t)3 * 4194304;
    u16*   Xp  = Abf;                         // reuse (Abf dead after k_proj)
    u16*   Xc  = QKV;                         // reuse Q segment (dead after k_attn)
    float* Lp  = (float*)(Abf + (size_t)3 * 4194304);

    k_prep<<<dim3(10240), 256, 0, stream>>>(q, k, v, Wq, Wk, Wv, Wo, Abf, Wt);
    k_proj<<<dim3(8, 32, 3), 256, 0, stream>>>(Abf, Wt, bq, bk, bv, QKV);
    k_attn<<<dim3(1536), 256, 0, stream>>>(QKV, QKV + (size_t)4194304,
                                           QKV + (size_t)2 * 4194304, Xp, Lp);
    k_combine<<<2048, 256, 0, stream>>>(Xp, Lp, Xc);
    k_gemm_out<<<dim3(8, 32), 256, 0, stream>>>(Xc, Wt + (size_t)3 * 1048576,
                                                bo, (float*)d_out);
}